// Round 1
// 274.827 us; speedup vs baseline: 1.1180x; 1.1180x over previous
//
#include <hip/hip_runtime.h>
#include <math.h>

#define WSZ 11
#define PAD 5
#define TX 32
#define TY 24
#define NY 6                 // y-tiles per block: 144 rows/block, 2160/144 = 15
#define IY (TY + 2*PAD)      // 34
#define RX 4                 // h-pass: 4 output px per task
#define NTASK0 (IY * 8)      // 272 tasks (s==0: full 34 rows)
#define NTASK1 (TY * 8)      // 192 tasks (s>0: only 24 new rows)
#define SEG (RX + 2*PAD)     // 14 input floats per task
#define RY 3                 // v-pass rows per thread (8 groups x 3 = 24)
#define SA 33                // sHA row stride in float4 (odd -> rotating banks)
#define SB 35                // sHB row stride in float (odd)

typedef float v2f __attribute__((ext_vector_type(2)));

struct W11 { float w[WSZ]; };

// R7 macro-structure (5400 blocks, contention-free partials) + R8 full-thread
// Phase A / register staging / interleaved LDS + R9 packed-f32 (v_pk_fma_f32).
// R10: rolling halo. The 2*PAD=10 halo rows were recomputed (and re-fetched)
// in EVERY s-tile: 204 h-pass row-passes per 144 output rows. Now the LDS
// buffer is shifted down by TY rows per tile (rows 24..33 -> 0..9, a tiny
// LDS->LDS copy) and Phase A computes only the 24 NEW rows. 204 -> 154
// row-passes (-25% of Phase A VALU + fetch). Buffer stays LINEAR so Phase B
// keeps compile-time ds_read offsets (a circular buffer would pay ~4 VALU/tap
// for wrap arithmetic). L1 ownership is now a global-row test so each output
// row is counted exactly once across tiles (29+24*4+19 = 144).
__global__ __launch_bounds__(256, 4) void ssim_l1_kernel(
    const float* __restrict__ pred, const float* __restrict__ targ,
    W11 wt, float2* __restrict__ partials)
{
    constexpr int H = 2160, W = 3840;
    __shared__ float4 sHA[IY][SA];   // {hp, ht, hpp, htt}   17.4 KB
    __shared__ float  sHB[IY][SB];   // hpt                   4.8 KB

    const int c    = blockIdx.z;
    const int gx0  = blockIdx.x * TX;
    const int base = blockIdx.y * (TY * NY);   // first output row of block
    const size_t plane = (size_t)H * W;
    const float* p = pred + (size_t)c * plane;
    const float* t = targ + (size_t)c * plane;

    const int tid = threadIdx.x;
    v2f loss_acc = {0.f, 0.f};       // .x = ssim, .y = l1
    const float C1v = 0.0001f, C2v = 0.0009f;

    const int oxB  = tid & 31;
    const int oy0B = (tid >> 5) * RY;
    const bool xfast = (blockIdx.x >= 1) && (blockIdx.x <= (W / TX) - 2);

    for (int s = 0; s < NY; ++s) {
        // ============ Phase A0 (s>0): shift halo rows 24..33 -> 0..9 =======
        if (s > 0) {
            for (int i = tid; i < 2 * PAD * TX; i += 256) {
                const int dr = i >> 5, cc = i & 31;
                sHA[dr][cc] = sHA[dr + TY][cc];
                sHB[dr][cc] = sHB[dr + TY][cc];
            }
            __syncthreads();
        }

        // ============ Phase A: horizontal 11-tap, global -> LDS ============
        // s==0: fill all 34 rows (buffer row rr = r, gy = base-5+rr).
        // s>0 : fill only rows 10..33 (rr = 10+r, gy = base+24s-5+rr).
        const int ntask  = (s == 0) ? NTASK0 : NTASK1;
        const int rowoff = (s == 0) ? 0 : 2 * PAD;
        const int gyA    = base + TY * s - PAD;      // gy = gyA + rr
        for (int task = tid; task < ntask; task += 256) {
            const int r  = task >> 3;
            const int cx = task & 7;
            const int rr = rowoff + r;               // LDS buffer row
            const int gy = gyA + rr;                 // global image row
            const int gxs = gx0 + cx * RX - PAD;     // input window e=0..13
            const bool rowok   = (gy >= 0) && (gy < H);
            const bool own_row = (gy >= base) && (gy < base + TY * NY);

            // 5 aligned float4 per image covering gxs-3 .. gxs+16 (registers only)
            float4 P[5], T[5];
            if (rowok && xfast) {
                const float4* p4 = (const float4*)(p + (size_t)gy * W + (gxs - 3));
                const float4* t4 = (const float4*)(t + (size_t)gy * W + (gxs - 3));
                #pragma unroll
                for (int i = 0; i < 5; ++i) { P[i] = p4[i]; T[i] = t4[i]; }
            } else if (rowok) {
                const size_t rowoff2 = (size_t)gy * W;
                #pragma unroll
                for (int i = 0; i < 5; ++i) {
                    float pe[4], te[4];
                    #pragma unroll
                    for (int q = 0; q < 4; ++q) {
                        int gx = gxs - 3 + 4 * i + q;
                        bool ok = (gx >= 0) && (gx < W);
                        pe[q] = ok ? p[rowoff2 + gx] : 0.f;
                        te[q] = ok ? t[rowoff2 + gx] : 0.f;
                    }
                    P[i] = make_float4(pe[0], pe[1], pe[2], pe[3]);
                    T[i] = make_float4(te[0], te[1], te[2], te[3]);
                }
            } else {
                #pragma unroll
                for (int i = 0; i < 5; ++i) {
                    P[i] = make_float4(0.f, 0.f, 0.f, 0.f);
                    T[i] = make_float4(0.f, 0.f, 0.f, 0.f);
                }
            }

            v2f h_ab[RX], h_sq[RX];
            float h_pt[RX];
            #pragma unroll
            for (int j = 0; j < RX; ++j) {
                h_ab[j] = (v2f){0.f, 0.f};
                h_sq[j] = (v2f){0.f, 0.f};
                h_pt[j] = 0.f;
            }
            #pragma unroll
            for (int e = 0; e < SEG; ++e) {
                const int ii = (e + 3) >> 2, qq = (e + 3) & 3;
                const float pe = (qq == 0) ? P[ii].x : (qq == 1) ? P[ii].y
                                : (qq == 2) ? P[ii].z : P[ii].w;
                const float te = (qq == 0) ? T[ii].x : (qq == 1) ? T[ii].y
                                : (qq == 2) ? T[ii].z : T[ii].w;
                v2f vab; vab.x = pe; vab.y = te;
                const v2f vsq = vab * vab;          // v_pk_mul_f32
                const float pt = pe * te;
                #pragma unroll
                for (int j = 0; j < RX; ++j) {
                    const int k = e - j;
                    if (k >= 0 && k < WSZ) {
                        const float wv = wt.w[k];
                        h_ab[j] += wv * vab;        // v_pk_fma_f32
                        h_sq[j] += wv * vsq;        // v_pk_fma_f32
                        h_pt[j] += wv * pt;
                    }
                }
                // L1 on owned pixels: each output row computed exactly once
                // across s-tiles now, so ownership = row in block's range.
                if (e >= PAD && e < PAD + RX && own_row)
                    loss_acc.y += fabsf(pe - te);
            }
            const int xb = cx * RX;
            #pragma unroll
            for (int j = 0; j < RX; ++j) {
                sHA[rr][xb + j] = make_float4(h_ab[j].x, h_ab[j].y,
                                              h_sq[j].x, h_sq[j].y);
                sHB[rr][xb + j] = h_pt[j];
            }
        }
        __syncthreads();

        // ============ Phase B: vertical 11-tap + SSIM ======================
        // Buffer is linear: row rr holds gy = base + 24s - 5 + rr, so the
        // read pattern (compile-time offsets) is identical to pre-R10.
        {
            v2f mu[RY], sq[RY];
            float sp[RY];
            #pragma unroll
            for (int j = 0; j < RY; ++j) {
                mu[j] = (v2f){0.f, 0.f};
                sq[j] = (v2f){0.f, 0.f};
                sp[j] = 0.f;
            }
            #pragma unroll
            for (int k = 0; k < RY + 2 * PAD; ++k) {
                const float4 f = sHA[oy0B + k][oxB];
                const float  g = sHB[oy0B + k][oxB];
                v2f fab; fab.x = f.x; fab.y = f.y;
                v2f fsq; fsq.x = f.z; fsq.y = f.w;
                #pragma unroll
                for (int j = 0; j < RY; ++j) {
                    const int kk = k - j;
                    if (kk >= 0 && kk < WSZ) {
                        const float wv = wt.w[kk];
                        mu[j] += wv * fab;          // v_pk_fma_f32
                        sq[j] += wv * fsq;          // v_pk_fma_f32
                        sp[j] += wv * g;
                    }
                }
            }
            #pragma unroll
            for (int j = 0; j < RY; ++j) {
                const float m1 = mu[j].x, m2 = mu[j].y;
                const float mu1s = m1 * m1;
                const float mu2s = m2 * m2;
                const float m12  = m1 * m2;
                const float num = (2.f * m12 + C1v) * (2.f * (sp[j] - m12) + C2v);
                const float den = (mu1s + mu2s + C1v)
                                * ((sq[j].x - mu1s) + (sq[j].y - mu2s) + C2v);
                loss_acc.x += num * __builtin_amdgcn_rcpf(den);
            }
        }
        __syncthreads();   // Phase B reads done before next shift/Phase A
    }

    // ============ block reduction -> contention-free partial ================
    #pragma unroll
    for (int off = 32; off > 0; off >>= 1) {
        loss_acc.x += __shfl_down(loss_acc.x, off, 64);
        loss_acc.y += __shfl_down(loss_acc.y, off, 64);
    }
    __shared__ float red[2][4];
    const int lane = tid & 63;
    const int wid  = tid >> 6;
    if (lane == 0) { red[0][wid] = loss_acc.x; red[1][wid] = loss_acc.y; }
    __syncthreads();
    if (tid == 0) {
        const float sv = red[0][0] + red[0][1] + red[0][2] + red[0][3];
        const float lv = red[1][0] + red[1][1] + red[1][2] + red[1][3];
        const int bid = (blockIdx.z * gridDim.y + blockIdx.y) * gridDim.x + blockIdx.x;
        partials[bid] = make_float2(sv, lv);
    }
}

__global__ __launch_bounds__(256) void finalize_kernel(
    const float2* __restrict__ partials, int n,
    float* __restrict__ out, double invN)
{
    const int tid = threadIdx.x;
    double s = 0.0, l = 0.0;
    for (int i = tid; i < n; i += 256) {
        float2 v = partials[i];
        s += (double)v.x;
        l += (double)v.y;
    }
    #pragma unroll
    for (int off = 32; off > 0; off >>= 1) {
        s += __shfl_down(s, off, 64);
        l += __shfl_down(l, off, 64);
    }
    __shared__ double rs[4], rl[4];
    const int lane = tid & 63, wid = tid >> 6;
    if (lane == 0) { rs[wid] = s; rl[wid] = l; }
    __syncthreads();
    if (tid == 0) {
        const double st = rs[0] + rs[1] + rs[2] + rs[3];
        const double lt = rl[0] + rl[1] + rl[2] + rl[3];
        out[0] = (float)(0.8 * lt * invN + 0.2 * (1.0 - st * invN));
    }
}

extern "C" void kernel_launch(void* const* d_in, const int* in_sizes, int n_in,
                              void* d_out, int out_size, void* d_ws, size_t ws_size,
                              hipStream_t stream)
{
    const float* pred = (const float*)d_in[0];
    const float* targ = (const float*)d_in[1];
    float* out = (float*)d_out;
    float2* partials = (float2*)d_ws;

    const int C = 3, H = 2160, W = 3840;

    W11 wt;
    double g[WSZ], sg = 0.0;
    for (int i = 0; i < WSZ; ++i) {
        double d = (double)i - (WSZ / 2);
        g[i] = exp(-(d * d) / (2.0 * 1.5 * 1.5));
        sg += g[i];
    }
    for (int i = 0; i < WSZ; ++i) wt.w[i] = (float)(g[i] / sg);

    dim3 grid(W / TX, H / (TY * NY), C);   // 120 x 15 x 3 = 5400 blocks
    ssim_l1_kernel<<<grid, 256, 0, stream>>>(pred, targ, wt, partials);

    const int nblocks = (W / TX) * (H / (TY * NY)) * C;
    double invN = 1.0 / ((double)C * (double)H * (double)W);
    finalize_kernel<<<1, 256, 0, stream>>>(partials, nblocks, out, invN);
}

// Round 2
// 246.815 us; speedup vs baseline: 1.2449x; 1.1135x over previous
//
#include <hip/hip_runtime.h>
#include <math.h>

#define WSZ 11
#define PAD 5
#define TX 32
#define TY 24
#define NY 6                 // y-tiles per block: 144 rows/block, 2160/144 = 15
#define IY (TY + 2*PAD)      // 34
#define RX 4                 // h-pass: 4 output px per task
#define NTASK0 (IY * 8)      // 272 tasks (s==0: full 34 rows)
#define NTASK1 (TY * 8)      // 192 tasks (s>0: only 24 new rows)
#define SEG (RX + 2*PAD)     // 14 input floats per task
#define RY 3                 // v-pass rows per thread (8 groups x 3 = 24)
#define SA 33                // sHA row stride in float4 (odd -> rotating banks)

typedef float v2f __attribute__((ext_vector_type(2)));

struct W11 { float w[WSZ]; };

// R7 macro-structure + R8 full-thread Phase A / register staging + R9 packed
// f32 + R10 rolling halo (204 -> 154 row-passes/block).
// R11: sum/difference reformulation. Convolve {s=p+t, d=p-t, s^2, d^2}
// (4 channels) instead of {p, t, p^2, t^2, p*t} (5 channels):
//   mu1*mu2       = (S^2 - D^2)/4        mu1^2+mu2^2 = (S^2 + D^2)/2
//   sigma12       = (Qs - Qd)/4 - (S^2 - D^2)/4
//   sig1^2+sig2^2 = (Qs + Qd)/2 - (S^2 + D^2)/2
// Every tap is now exactly 2 v_pk_fma_f32 (was 2 pk + 1 scalar fma), the
// scalar hpt pipeline and the sHB LDS buffer disappear (5 -> 4 floats/px,
// LDS 23 -> 18 KB -> 8 blocks/CU headroom), and L1 reuses d directly.
__global__ __launch_bounds__(256, 4) void ssim_l1_kernel(
    const float* __restrict__ pred, const float* __restrict__ targ,
    W11 wt, float2* __restrict__ partials)
{
    constexpr int H = 2160, W = 3840;
    __shared__ float4 sHA[IY][SA];   // {hs, hd, hss, hdd}   17.95 KB

    const int c    = blockIdx.z;
    const int gx0  = blockIdx.x * TX;
    const int base = blockIdx.y * (TY * NY);   // first output row of block
    const size_t plane = (size_t)H * W;
    const float* p = pred + (size_t)c * plane;
    const float* t = targ + (size_t)c * plane;

    const int tid = threadIdx.x;
    v2f loss_acc = {0.f, 0.f};       // .x = ssim, .y = l1
    const float C1v = 0.0001f, C2v = 0.0009f;

    const int oxB  = tid & 31;
    const int oy0B = (tid >> 5) * RY;
    const bool xfast = (blockIdx.x >= 1) && (blockIdx.x <= (W / TX) - 2);

    for (int s = 0; s < NY; ++s) {
        // ============ Phase A0 (s>0): shift halo rows 24..33 -> 0..9 =======
        if (s > 0) {
            for (int i = tid; i < 2 * PAD * TX; i += 256) {
                const int dr = i >> 5, cc = i & 31;
                sHA[dr][cc] = sHA[dr + TY][cc];
            }
            __syncthreads();
        }

        // ============ Phase A: horizontal 11-tap, global -> LDS ============
        const int ntask  = (s == 0) ? NTASK0 : NTASK1;
        const int rowoff = (s == 0) ? 0 : 2 * PAD;
        const int gyA    = base + TY * s - PAD;      // gy = gyA + rr
        for (int task = tid; task < ntask; task += 256) {
            const int r  = task >> 3;
            const int cx = task & 7;
            const int rr = rowoff + r;               // LDS buffer row
            const int gy = gyA + rr;                 // global image row
            const int gxs = gx0 + cx * RX - PAD;     // input window e=0..13
            const bool rowok   = (gy >= 0) && (gy < H);
            const bool own_row = (gy >= base) && (gy < base + TY * NY);

            // 5 aligned float4 per image covering gxs-3 .. gxs+16 (registers)
            float4 P[5], T[5];
            if (rowok && xfast) {
                const float4* p4 = (const float4*)(p + (size_t)gy * W + (gxs - 3));
                const float4* t4 = (const float4*)(t + (size_t)gy * W + (gxs - 3));
                #pragma unroll
                for (int i = 0; i < 5; ++i) { P[i] = p4[i]; T[i] = t4[i]; }
            } else if (rowok) {
                const size_t rowoff2 = (size_t)gy * W;
                #pragma unroll
                for (int i = 0; i < 5; ++i) {
                    float pe[4], te[4];
                    #pragma unroll
                    for (int q = 0; q < 4; ++q) {
                        int gx = gxs - 3 + 4 * i + q;
                        bool ok = (gx >= 0) && (gx < W);
                        pe[q] = ok ? p[rowoff2 + gx] : 0.f;
                        te[q] = ok ? t[rowoff2 + gx] : 0.f;
                    }
                    P[i] = make_float4(pe[0], pe[1], pe[2], pe[3]);
                    T[i] = make_float4(te[0], te[1], te[2], te[3]);
                }
            } else {
                #pragma unroll
                for (int i = 0; i < 5; ++i) {
                    P[i] = make_float4(0.f, 0.f, 0.f, 0.f);
                    T[i] = make_float4(0.f, 0.f, 0.f, 0.f);
                }
            }

            v2f h_sd[RX], h_qq[RX];
            #pragma unroll
            for (int j = 0; j < RX; ++j) {
                h_sd[j] = (v2f){0.f, 0.f};
                h_qq[j] = (v2f){0.f, 0.f};
            }
            #pragma unroll
            for (int e = 0; e < SEG; ++e) {
                const int ii = (e + 3) >> 2, qq = (e + 3) & 3;
                const float pe = (qq == 0) ? P[ii].x : (qq == 1) ? P[ii].y
                                : (qq == 2) ? P[ii].z : P[ii].w;
                const float te = (qq == 0) ? T[ii].x : (qq == 1) ? T[ii].y
                                : (qq == 2) ? T[ii].z : T[ii].w;
                v2f vsd; vsd.x = pe + te; vsd.y = pe - te;
                const v2f vsq = vsd * vsd;          // v_pk_mul_f32
                #pragma unroll
                for (int j = 0; j < RX; ++j) {
                    const int k = e - j;
                    if (k >= 0 && k < WSZ) {
                        const float wv = wt.w[k];
                        h_sd[j] += wv * vsd;        // v_pk_fma_f32
                        h_qq[j] += wv * vsq;        // v_pk_fma_f32
                    }
                }
                // L1 on owned pixels: d = p - t already in vsd.y
                if (e >= PAD && e < PAD + RX && own_row)
                    loss_acc.y += fabsf(vsd.y);
            }
            const int xb = cx * RX;
            #pragma unroll
            for (int j = 0; j < RX; ++j)
                sHA[rr][xb + j] = make_float4(h_sd[j].x, h_sd[j].y,
                                              h_qq[j].x, h_qq[j].y);
        }
        __syncthreads();

        // ============ Phase B: vertical 11-tap + SSIM ======================
        {
            v2f mu[RY], qq[RY];
            #pragma unroll
            for (int j = 0; j < RY; ++j) {
                mu[j] = (v2f){0.f, 0.f};
                qq[j] = (v2f){0.f, 0.f};
            }
            #pragma unroll
            for (int k = 0; k < RY + 2 * PAD; ++k) {
                const float4 f = sHA[oy0B + k][oxB];
                v2f fsd; fsd.x = f.x; fsd.y = f.y;
                v2f fsq; fsq.x = f.z; fsq.y = f.w;
                #pragma unroll
                for (int j = 0; j < RY; ++j) {
                    const int kk = k - j;
                    if (kk >= 0 && kk < WSZ) {
                        const float wv = wt.w[kk];
                        mu[j] += wv * fsd;          // v_pk_fma_f32
                        qq[j] += wv * fsq;          // v_pk_fma_f32
                    }
                }
            }
            #pragma unroll
            for (int j = 0; j < RY; ++j) {
                const v2f musq = mu[j] * mu[j];     // (S^2, D^2)  v_pk_mul
                const v2f rr2  = qq[j] - musq;      // (Qs-S^2, Qd-D^2)
                // 2*mu1*mu2 + C1 = (S^2 - D^2)/2 + C1
                const float a  = 0.5f * (musq.x - musq.y) + C1v;
                // 2*sigma12 + C2 = (rr2.x - rr2.y)/2 + C2
                const float b  = 0.5f * (rr2.x - rr2.y) + C2v;
                // mu1^2 + mu2^2 + C1 = (S^2 + D^2)/2 + C1
                const float cden = 0.5f * (musq.x + musq.y) + C1v;
                // sig1^2 + sig2^2 + C2 = (rr2.x + rr2.y)/2 + C2
                const float dden = 0.5f * (rr2.x + rr2.y) + C2v;
                loss_acc.x += (a * b) * __builtin_amdgcn_rcpf(cden * dden);
            }
        }
        __syncthreads();   // Phase B reads done before next shift/Phase A
    }

    // ============ block reduction -> contention-free partial ================
    #pragma unroll
    for (int off = 32; off > 0; off >>= 1) {
        loss_acc.x += __shfl_down(loss_acc.x, off, 64);
        loss_acc.y += __shfl_down(loss_acc.y, off, 64);
    }
    __shared__ float red[2][4];
    const int lane = tid & 63;
    const int wid  = tid >> 6;
    if (lane == 0) { red[0][wid] = loss_acc.x; red[1][wid] = loss_acc.y; }
    __syncthreads();
    if (tid == 0) {
        const float sv = red[0][0] + red[0][1] + red[0][2] + red[0][3];
        const float lv = red[1][0] + red[1][1] + red[1][2] + red[1][3];
        const int bid = (blockIdx.z * gridDim.y + blockIdx.y) * gridDim.x + blockIdx.x;
        partials[bid] = make_float2(sv, lv);
    }
}

__global__ __launch_bounds__(256) void finalize_kernel(
    const float2* __restrict__ partials, int n,
    float* __restrict__ out, double invN)
{
    const int tid = threadIdx.x;
    double s = 0.0, l = 0.0;
    for (int i = tid; i < n; i += 256) {
        float2 v = partials[i];
        s += (double)v.x;
        l += (double)v.y;
    }
    #pragma unroll
    for (int off = 32; off > 0; off >>= 1) {
        s += __shfl_down(s, off, 64);
        l += __shfl_down(l, off, 64);
    }
    __shared__ double rs[4], rl[4];
    const int lane = tid & 63, wid = tid >> 6;
    if (lane == 0) { rs[wid] = s; rl[wid] = l; }
    __syncthreads();
    if (tid == 0) {
        const double st = rs[0] + rs[1] + rs[2] + rs[3];
        const double lt = rl[0] + rl[1] + rl[2] + rl[3];
        out[0] = (float)(0.8 * lt * invN + 0.2 * (1.0 - st * invN));
    }
}

extern "C" void kernel_launch(void* const* d_in, const int* in_sizes, int n_in,
                              void* d_out, int out_size, void* d_ws, size_t ws_size,
                              hipStream_t stream)
{
    const float* pred = (const float*)d_in[0];
    const float* targ = (const float*)d_in[1];
    float* out = (float*)d_out;
    float2* partials = (float2*)d_ws;

    const int C = 3, H = 2160, W = 3840;

    W11 wt;
    double g[WSZ], sg = 0.0;
    for (int i = 0; i < WSZ; ++i) {
        double d = (double)i - (WSZ / 2);
        g[i] = exp(-(d * d) / (2.0 * 1.5 * 1.5));
        sg += g[i];
    }
    for (int i = 0; i < WSZ; ++i) wt.w[i] = (float)(g[i] / sg);

    dim3 grid(W / TX, H / (TY * NY), C);   // 120 x 15 x 3 = 5400 blocks
    ssim_l1_kernel<<<grid, 256, 0, stream>>>(pred, targ, wt, partials);

    const int nblocks = (W / TX) * (H / (TY * NY)) * C;
    double invN = 1.0 / ((double)C * (double)H * (double)W);
    finalize_kernel<<<1, 256, 0, stream>>>(partials, nblocks, out, invN);
}